// Round 1
// baseline (478.136 us; speedup 1.0000x reference)
//
#include <hip/hip_runtime.h>

#define T_STEPS 127
#define BATCH   256
#define VOCAB   512
#define HID     1024
#define MROWS   (T_STEPS * BATCH)   // 32512 = 254 * 128
#define BHID    (BATCH * HID)       // 262144

typedef __attribute__((ext_vector_type(4))) float f32x4;
typedef __attribute__((ext_vector_type(8))) short s16x8;
typedef unsigned short u16;

__device__ __forceinline__ u16 f2bf(float f) {
    union { float f; unsigned u; } c; c.f = f;
    unsigned u = c.u;
    u += 0x7FFFu + ((u >> 16) & 1u);   // round-to-nearest-even
    return (u16)(u >> 16);
}

// ---------------- fp32 -> bf16 convert, 4 elems/thread ----------------
__global__ __launch_bounds__(256) void cvt_kernel(const float* __restrict__ in,
                                                  u16* __restrict__ out, int n4) {
    int i = blockIdx.x * 256 + threadIdx.x;
    if (i >= n4) return;
    f32x4 v = ((const f32x4*)in)[i];
    ushort4 o;
    o.x = f2bf(v[0]); o.y = f2bf(v[1]); o.z = f2bf(v[2]); o.w = f2bf(v[3]);
    ((ushort4*)out)[i] = o;
}

// ---------------- leaky scan: v[t] = beta*v[t-1] + x[t]; fp32 in, bf16 out ----
__global__ __launch_bounds__(256) void scan_kernel(const float* __restrict__ in,
                                                   u16* __restrict__ out,
                                                   const float* __restrict__ beta) {
    int i4   = blockIdx.x * 256 + threadIdx.x;   // 0 .. BHID/4-1
    int base = i4 * 4;
    int hh   = base & (HID - 1);
    f32x4 bt = *(const f32x4*)(beta + hh);
    f32x4 v  = {0.f, 0.f, 0.f, 0.f};
    const float* ip = in + base;
    u16*         op = out + base;
    for (int t = 0; t < T_STEPS; ++t) {
        f32x4 xv = *(const f32x4*)ip;
        v = bt * v + xv;
        ushort4 o;
        o.x = f2bf(v[0]); o.y = f2bf(v[1]); o.z = f2bf(v[2]); o.w = f2bf(v[3]);
        *(ushort4*)op = o;
        ip += BHID; op += BHID;
    }
}

// ---------------- bf16 MFMA GEMM: C[m,n] = sum_k A[m,k]*B[n,k] + bias[n] ------
// A: [M][K] bf16 row-major, B: [N][K] bf16 row-major (i.e. weights [out,in]),
// C: [M][N] fp32. M fixed at MROWS. Tiles 128x128, BK=32, 4 waves (2x2).
#define BM 128
#define BN 128
#define BK 32

#define GLDS16(g, l) __builtin_amdgcn_global_load_lds(                      \
        (const __attribute__((address_space(1))) void*)(g),                 \
        (__attribute__((address_space(3))) void*)(l), 16, 0, 0)

template <bool RELU>
__global__ __launch_bounds__(256) void gemm_bt(const u16* __restrict__ A,
                                               const u16* __restrict__ B,
                                               const float* __restrict__ bias,
                                               float* __restrict__ C,
                                               int N, int K) {
    __shared__ u16 As[BM * BK];
    __shared__ u16 Bs[BN * BK];

    // XCD-aware swizzle (all our grids are divisible by 8)
    int nwg = gridDim.x;
    int wg  = blockIdx.x;
    int cpx = nwg >> 3;
    wg = (wg & 7) * cpx + (wg >> 3);

    int ntiles = N / BN;
    int mt = wg / ntiles;
    int nt = wg - mt * ntiles;

    int tid  = threadIdx.x;
    int wave = tid >> 6;
    int lane = tid & 63;
    int wr   = wave >> 1;   // wave row (0..1) -> 64 rows
    int wc   = wave & 1;    // wave col (0..1) -> 64 cols

    const u16* Ab = A + (size_t)mt * BM * K;
    const u16* Bb = B + (size_t)nt * BN * K;

    // staging geometry: each wave stages 16 rows per half; lane -> (row, 16B chunk)
    int srow = (wave << 4) + (lane >> 2);   // 0..63 within a 64-row half
    int scol = (lane & 3) << 3;             // element offset of 16B chunk

    // fragment-read geometry
    int lr = lane & 15;
    int kq = (lane >> 4) << 3;
    const u16* ap = As + ((wr << 6) + lr) * BK + kq;
    const u16* bp = Bs + ((wc << 6) + lr) * BK + kq;

    f32x4 acc[4][4] = {};

    for (int kt = 0; kt < K; kt += BK) {
        // stage A and B tiles: two 64-row halves each, 16B per lane
        GLDS16(Ab + (size_t)srow * K + kt + scol,        As + (wave << 4) * BK);
        GLDS16(Ab + (size_t)(64 + srow) * K + kt + scol, As + (64 + (wave << 4)) * BK);
        GLDS16(Bb + (size_t)srow * K + kt + scol,        Bs + (wave << 4) * BK);
        GLDS16(Bb + (size_t)(64 + srow) * K + kt + scol, Bs + (64 + (wave << 4)) * BK);
        __syncthreads();   // drains vmcnt + barrier

        s16x8 af[4], bf[4];
#pragma unroll
        for (int m = 0; m < 4; ++m) af[m] = *(const s16x8*)(ap + m * 16 * BK);
#pragma unroll
        for (int n = 0; n < 4; ++n) bf[n] = *(const s16x8*)(bp + n * 16 * BK);
#pragma unroll
        for (int m = 0; m < 4; ++m)
#pragma unroll
            for (int n = 0; n < 4; ++n)
                acc[m][n] = __builtin_amdgcn_mfma_f32_16x16x32_bf16(
                    af[m], bf[n], acc[m][n], 0, 0, 0);
        __syncthreads();   // protect LDS before next stage
    }

    // epilogue: C/D layout col = lane&15, row = (lane>>4)*4 + j  [m89 verified]
    int r0 = mt * BM + (wr << 6) + ((lane >> 4) << 2);
    int c0 = nt * BN + (wc << 6) + lr;
#pragma unroll
    for (int n = 0; n < 4; ++n) {
        float bb = bias[c0 + n * 16];
#pragma unroll
        for (int m = 0; m < 4; ++m)
#pragma unroll
            for (int j = 0; j < 4; ++j) {
                float v = acc[m][n][j] + bb;
                if (RELU) v = v > 0.f ? v : 0.f;
                C[(size_t)(r0 + (m << 4) + j) * N + c0 + n * 16] = v;
            }
    }
}

// ---------------------------------------------------------------------------
extern "C" void kernel_launch(void* const* d_in, const int* in_sizes, int n_in,
                              void* d_out, int out_size, void* d_ws, size_t ws_size,
                              hipStream_t stream) {
    const float* x   = (const float*)d_in[0];
    const float* W1  = (const float*)d_in[1];
    const float* b1  = (const float*)d_in[2];
    const float* bt1 = (const float*)d_in[3];
    const float* W2  = (const float*)d_in[4];
    const float* b2  = (const float*)d_in[5];
    const float* bt2 = (const float*)d_in[6];
    const float* W3  = (const float*)d_in[7];
    const float* b3  = (const float*)d_in[8];
    const float* bt3 = (const float*)d_in[9];
    const float* W4  = (const float*)d_in[10];
    const float* b4  = (const float*)d_in[11];

    char* ws = (char*)d_ws;
    float* h  = (float*)ws;                              // 133,169,152 B (fp32 [M][H])
    u16*   hs = (u16*)(ws + (size_t)MROWS * HID * 4);    //  66,584,576 B (bf16 [M][H])
    u16*   xb = hs;  // overlap: x_bf16 consumed by GEMM1 before scan1 writes hs
    char* wp = ws + (size_t)MROWS * HID * 4 + (size_t)MROWS * HID * 2;
    u16* W1b = (u16*)wp; wp += (size_t)HID * VOCAB * 2;
    u16* W2b = (u16*)wp; wp += (size_t)HID * HID * 2;
    u16* W3b = (u16*)wp; wp += (size_t)HID * HID * 2;
    u16* W4b = (u16*)wp;

    // fp32 -> bf16 conversions
    cvt_kernel<<<dim3((MROWS * VOCAB / 4 + 255) / 256), dim3(256), 0, stream>>>(
        x, xb, MROWS * VOCAB / 4);
    cvt_kernel<<<dim3(512),  dim3(256), 0, stream>>>(W1, W1b, HID * VOCAB / 4);
    cvt_kernel<<<dim3(1024), dim3(256), 0, stream>>>(W2, W2b, HID * HID / 4);
    cvt_kernel<<<dim3(1024), dim3(256), 0, stream>>>(W3, W3b, HID * HID / 4);
    cvt_kernel<<<dim3(512),  dim3(256), 0, stream>>>(W4, W4b, VOCAB * HID / 4);

    const int MT = MROWS / BM;  // 254

    // fc1 + scan1
    gemm_bt<false><<<dim3(MT * (HID / BN)), dim3(256), 0, stream>>>(xb, W1b, b1, h, HID, VOCAB);
    scan_kernel<<<dim3(BHID / 4 / 256), dim3(256), 0, stream>>>(h, hs, bt1);
    // fc2 (relu) + scan2
    gemm_bt<true><<<dim3(MT * (HID / BN)), dim3(256), 0, stream>>>(hs, W2b, b2, h, HID, HID);
    scan_kernel<<<dim3(BHID / 4 / 256), dim3(256), 0, stream>>>(h, hs, bt2);
    // fc3 (relu) + scan3
    gemm_bt<true><<<dim3(MT * (HID / BN)), dim3(256), 0, stream>>>(hs, W3b, b3, h, HID, HID);
    scan_kernel<<<dim3(BHID / 4 / 256), dim3(256), 0, stream>>>(h, hs, bt3);
    // fc4 -> d_out (fp32)
    gemm_bt<false><<<dim3(MT * (VOCAB / BN)), dim3(256), 0, stream>>>(
        hs, W4b, b4, (float*)d_out, VOCAB, HID);
}

// Round 3
// 379.302 us; speedup vs baseline: 1.2606x; 1.2606x over previous
//
#include <hip/hip_runtime.h>

#define T_STEPS 127
#define BATCH   256
#define VOCAB   512
#define HID     1024
#define MROWS   (T_STEPS * BATCH)   // 32512 = 127 * 256
#define BHID    (BATCH * HID)       // 262144

typedef __attribute__((ext_vector_type(4))) float f32x4;
typedef __attribute__((ext_vector_type(8))) short s16x8;
typedef unsigned short u16;

__device__ __forceinline__ u16 f2bf(float f) {
    union { float f; unsigned u; } c; c.f = f;
    unsigned u = c.u;
    u += 0x7FFFu + ((u >> 16) & 1u);   // RNE
    return (u16)(u >> 16);
}
__device__ __forceinline__ float bf2f(u16 x) {
    union { float f; unsigned u; } c; c.u = ((unsigned)x) << 16;
    return c.f;
}

// ---------------- fp32 -> bf16 convert, 4 elems/thread ----------------
__global__ __launch_bounds__(256) void cvt_kernel(const float* __restrict__ in,
                                                  u16* __restrict__ out, int n4) {
    int i = blockIdx.x * 256 + threadIdx.x;
    if (i >= n4) return;
    f32x4 v = ((const f32x4*)in)[i];
    ushort4 o;
    o.x = f2bf(v[0]); o.y = f2bf(v[1]); o.z = f2bf(v[2]); o.w = f2bf(v[3]);
    ((ushort4*)out)[i] = o;
}

// ------------- leaky scan: bf16 in, bf16 out, fp32 state; 2 elems/thread -----
__global__ __launch_bounds__(256) void scan2_kernel(const u16* __restrict__ in,
                                                    u16* __restrict__ out,
                                                    const float* __restrict__ beta) {
    int i2   = blockIdx.x * 256 + threadIdx.x;   // 0 .. BHID/2-1
    int base = i2 * 2;
    int hh   = base & (HID - 1);
    float b0 = beta[hh], b1 = beta[hh + 1];
    float v0 = 0.f, v1 = 0.f;
    const u16* ip = in + base;
    u16*       op = out + base;
    for (int t = 0; t < T_STEPS; ++t) {
        ushort2 xv = *(const ushort2*)ip;
        v0 = b0 * v0 + bf2f(xv.x);
        v1 = b1 * v1 + bf2f(xv.y);
        ushort2 o; o.x = f2bf(v0); o.y = f2bf(v1);
        *(ushort2*)op = o;
        ip += BHID; op += BHID;
    }
}

// ---------------- 256x256 8-phase bf16 MFMA GEMM ----------------------------
// A: [M][K] bf16 row-major, B: [N][K] bf16 row-major. C row-major [M][N].
// 512 threads = 8 waves (2M x 4N). BK=64. LDS 128 KiB double-buffered.
// XOR swizzle: LDS chunk slot s of row r holds global chunk s^(r&7); applied
// on the global SOURCE addr (global_load_lds dest is linear) and on ds_read.
// Sync discipline: vmcnt(N) BEFORE a phase-final barrier; dependent ds_reads
// AFTER it (vmcnt is per-wave; the barrier makes it workgroup-wide).

#define GLDS16(g, l) __builtin_amdgcn_global_load_lds(                      \
        (const __attribute__((address_space(1))) void*)(g),                 \
        (__attribute__((address_space(3))) void*)(l), 16, 0, 0)

template <int QM, int QN, int VMCNT, class S>
__device__ __forceinline__ void do_phase(const u16* lds, f32x4 (&acc)[8][4],
                                         int ab, int bb, int sw0, int sw1,
                                         S&& stage) {
    s16x8 af[4][2], bf[2][2];
#pragma unroll
    for (int i = 0; i < 4; ++i) {
        const u16* p = lds + ab + (QM * 64 + i * 16) * 64;
        af[i][0] = *(const s16x8*)(p + sw0);
        af[i][1] = *(const s16x8*)(p + sw1);
    }
#pragma unroll
    for (int j = 0; j < 2; ++j) {
        const u16* p = lds + bb + (QN * 32 + j * 16) * 64;
        bf[j][0] = *(const s16x8*)(p + sw0);
        bf[j][1] = *(const s16x8*)(p + sw1);
    }
    stage();
    __builtin_amdgcn_s_barrier();
    __builtin_amdgcn_s_setprio(1);
#pragma unroll
    for (int i = 0; i < 4; ++i)
#pragma unroll
        for (int j = 0; j < 2; ++j) {
            acc[QM * 4 + i][QN * 2 + j] = __builtin_amdgcn_mfma_f32_16x16x32_bf16(
                af[i][0], bf[j][0], acc[QM * 4 + i][QN * 2 + j], 0, 0, 0);
            acc[QM * 4 + i][QN * 2 + j] = __builtin_amdgcn_mfma_f32_16x16x32_bf16(
                af[i][1], bf[j][1], acc[QM * 4 + i][QN * 2 + j], 0, 0, 0);
        }
    __builtin_amdgcn_s_setprio(0);
    if constexpr (VMCNT == 8) asm volatile("s_waitcnt vmcnt(8)" ::: "memory");
    if constexpr (VMCNT == 4) asm volatile("s_waitcnt vmcnt(4)" ::: "memory");
    __builtin_amdgcn_s_barrier();
}

template <bool RELU, typename OutT>
__global__ __launch_bounds__(512, 2) void gemm8(const u16* __restrict__ A,
                                                const u16* __restrict__ B,
                                                const float* __restrict__ bias,
                                                OutT* __restrict__ C,
                                                int N, int K) {
    __shared__ u16 lds[65536];   // [buf0: A 16K | B 16K][buf1: A 16K | B 16K]

    const int tid  = threadIdx.x;
    const int wv   = tid >> 6;
    const int lane = tid & 63;
    const int wr   = wv >> 2;     // 0..1 -> 128 rows
    const int wc   = wv & 3;      // 0..3 -> 64 cols
    const int lr   = lane & 15;

    // bijective XCD swizzle (m204) — grids 508/254 are not %8
    int nwg = gridDim.x, orig = blockIdx.x;
    int qq = nwg >> 3, rr = nwg & 7, xcd = orig & 7, lin = orig >> 3;
    int wg = (xcd < rr ? xcd * (qq + 1) : rr * (qq + 1) + (xcd - rr) * qq) + lin;

    const int NT = N >> 8;
    const int mt = wg / NT, nt = wg % NT;

    const u16* Ag = A + (size_t)mt * 256 * K;
    const u16* Bg = B + (size_t)nt * 256 * K;

    // staging geometry: one GLDS16 by 512 threads = 64 rows x 128 B
    const int grow  = tid >> 3;                       // row within 64-row load
    const int gcol  = 8 * ((tid & 7) ^ (grow & 7));   // swizzled elem col
    const int wbase = wv * 512;                       // wave's 8-row LDS block

#define STAGE_A(j, buf, kt) GLDS16(Ag + (size_t)((j) * 64 + grow) * K + (kt) + gcol, \
                                   lds + (buf) * 32768 + (j) * 4096 + wbase)
#define STAGE_B(j, buf, kt) GLDS16(Bg + (size_t)((j) * 64 + grow) * K + (kt) + gcol, \
                                   lds + (buf) * 32768 + 16384 + (j) * 4096 + wbase)

    // ds-read swizzle constants (row&7 == lane&7 for all fragment rows)
    const int sw0 = 8 * (((lane >> 4)) ^ (lane & 7));
    const int sw1 = 8 * ((4 | (lane >> 4)) ^ (lane & 7));
    const int arow = (wr * 128 + lr) * 64;
    const int brow = (wc * 64 + lr) * 64;

    f32x4 acc[8][4] = {};
    const int NKT = K >> 6;

    // prologue: tile0 (A02, B0-3, A13), tile1 A02  -> 10 loads in flight
    STAGE_A(0, 0, 0); STAGE_A(2, 0, 0);
    STAGE_B(0, 0, 0); STAGE_B(1, 0, 0); STAGE_B(2, 0, 0); STAGE_B(3, 0, 0);
    STAGE_A(1, 0, 0); STAGE_A(3, 0, 0);
    STAGE_A(0, 1, 64); STAGE_A(2, 1, 64);
    // retire tile0 A02+B for ALL waves before first read
    asm volatile("s_waitcnt vmcnt(4)" ::: "memory");
    __builtin_amdgcn_s_barrier();

    for (int t = 0; t < NKT; ++t) {
        const int buf = t & 1, nbuf = buf ^ 1;
        const int t1 = (t + 1 < NKT) ? t + 1 : NKT - 1;
        const int t2 = (t + 2 < NKT) ? t + 2 : NKT - 1;
        const int kt1 = t1 << 6, kt2 = t2 << 6;
        const int ab = buf * 32768 + arow;
        const int bb = buf * 32768 + 16384 + brow;

        do_phase<0, 0, -1>(lds, acc, ab, bb, sw0, sw1, [&] {
            STAGE_B(0, nbuf, kt1); STAGE_B(1, nbuf, kt1);
            STAGE_B(2, nbuf, kt1); STAGE_B(3, nbuf, kt1);
        });
        // vmcnt(8) at end of this phase retires A13(t) for phase<1,0>
        do_phase<0, 1, 8>(lds, acc, ab, bb, sw0, sw1, [&] {
            STAGE_A(1, nbuf, kt1); STAGE_A(3, nbuf, kt1);
        });
        do_phase<1, 0, -1>(lds, acc, ab, bb, sw0, sw1, [&] {
            STAGE_A(0, buf, kt2); STAGE_A(2, buf, kt2);
        });
        // vmcnt(4) retires A02(t+1)+B(t+1) for next iteration's phase<0,0>
        do_phase<1, 1, 4>(lds, acc, ab, bb, sw0, sw1, [&] {});
    }

    // epilogue: C/D layout col = lane&15, row = (lane>>4)*4 + j
    const int r0 = mt * 256 + wr * 128 + ((lane >> 4) << 2);
    const int c0 = nt * 256 + wc * 64 + lr;
#pragma unroll
    for (int n = 0; n < 4; ++n) {
        float bb2 = bias[c0 + n * 16];
#pragma unroll
        for (int m = 0; m < 8; ++m)
#pragma unroll
            for (int j = 0; j < 4; ++j) {
                float v = acc[m][n][j] + bb2;
                if (RELU) v = v > 0.f ? v : 0.f;
                size_t idx = (size_t)(r0 + m * 16 + j) * N + (c0 + n * 16);
                if constexpr (sizeof(OutT) == 2) C[idx] = (OutT)f2bf(v);
                else                             C[idx] = v;
            }
    }
#undef STAGE_A
#undef STAGE_B
}

// ---------------------------------------------------------------------------
extern "C" void kernel_launch(void* const* d_in, const int* in_sizes, int n_in,
                              void* d_out, int out_size, void* d_ws, size_t ws_size,
                              hipStream_t stream) {
    const float* x   = (const float*)d_in[0];
    const float* W1  = (const float*)d_in[1];
    const float* b1  = (const float*)d_in[2];
    const float* bt1 = (const float*)d_in[3];
    const float* W2  = (const float*)d_in[4];
    const float* b2  = (const float*)d_in[5];
    const float* bt2 = (const float*)d_in[6];
    const float* W3  = (const float*)d_in[7];
    const float* b3  = (const float*)d_in[8];
    const float* bt3 = (const float*)d_in[9];
    const float* W4  = (const float*)d_in[10];
    const float* b4  = (const float*)d_in[11];

    char* ws = (char*)d_ws;
    u16* h  = (u16*)ws;                                  // bf16 [M][H] GEMM out
    u16* hs = (u16*)(ws + (size_t)MROWS * HID * 2);      // bf16 [M][H] scan out
    u16* xb = hs;  // x_bf16 overlaps hs: consumed by GEMM1 before scan1 writes
    char* wp = ws + (size_t)MROWS * HID * 2 * 2;
    u16* W1b = (u16*)wp; wp += (size_t)HID * VOCAB * 2;
    u16* W2b = (u16*)wp; wp += (size_t)HID * HID * 2;
    u16* W3b = (u16*)wp; wp += (size_t)HID * HID * 2;
    u16* W4b = (u16*)wp;

    cvt_kernel<<<dim3((MROWS * VOCAB / 4 + 255) / 256), dim3(256), 0, stream>>>(
        x, xb, MROWS * VOCAB / 4);
    cvt_kernel<<<dim3(512),  dim3(256), 0, stream>>>(W1, W1b, HID * VOCAB / 4);
    cvt_kernel<<<dim3(1024), dim3(256), 0, stream>>>(W2, W2b, HID * HID / 4);
    cvt_kernel<<<dim3(1024), dim3(256), 0, stream>>>(W3, W3b, HID * HID / 4);
    cvt_kernel<<<dim3(512),  dim3(256), 0, stream>>>(W4, W4b, VOCAB * HID / 4);

    const int MT = MROWS / 256;  // 127

    // fc1 + scan1
    gemm8<false, u16><<<dim3(MT * (HID / 256)), dim3(512), 0, stream>>>(
        xb, W1b, b1, h, HID, VOCAB);
    scan2_kernel<<<dim3(BHID / 2 / 256), dim3(256), 0, stream>>>(h, hs, bt1);
    // fc2 (relu) + scan2
    gemm8<true, u16><<<dim3(MT * (HID / 256)), dim3(512), 0, stream>>>(
        hs, W2b, b2, h, HID, HID);
    scan2_kernel<<<dim3(BHID / 2 / 256), dim3(256), 0, stream>>>(h, hs, bt2);
    // fc3 (relu) + scan3
    gemm8<true, u16><<<dim3(MT * (VOCAB / 256) * 2), dim3(512), 0, stream>>>(
        hs, W3b, b3, h, HID, HID);
    scan2_kernel<<<dim3(BHID / 2 / 256), dim3(256), 0, stream>>>(h, hs, bt3);
    // fc4 -> d_out (fp32)
    gemm8<false, float><<<dim3(MT * (VOCAB / 256)), dim3(512), 0, stream>>>(
        hs, W4b, b4, (float*)d_out, VOCAB, HID);
}

// Round 4
// 333.015 us; speedup vs baseline: 1.4358x; 1.1390x over previous
//
#include <hip/hip_runtime.h>

#define T_STEPS 127
#define BATCH   256
#define VOCAB   512
#define HID     1024
#define MROWS   (T_STEPS * BATCH)   // 32512 = 127 * 256
#define BHID    (BATCH * HID)       // 262144

typedef __attribute__((ext_vector_type(4))) float f32x4;
typedef __attribute__((ext_vector_type(8))) short s16x8;
typedef unsigned short u16;

__device__ __forceinline__ u16 f2bf(float f) {
    union { float f; unsigned u; } c; c.f = f;
    unsigned u = c.u;
    u += 0x7FFFu + ((u >> 16) & 1u);   // RNE
    return (u16)(u >> 16);
}
__device__ __forceinline__ float bf2f(u16 x) {
    union { float f; unsigned u; } c; c.u = ((unsigned)x) << 16;
    return c.f;
}

// ---------------- fp32 -> bf16 convert, 4 elems/thread ----------------
__global__ __launch_bounds__(256) void cvt_kernel(const float* __restrict__ in,
                                                  u16* __restrict__ out, int n4) {
    int i = blockIdx.x * 256 + threadIdx.x;
    if (i >= n4) return;
    f32x4 v = ((const f32x4*)in)[i];
    ushort4 o;
    o.x = f2bf(v[0]); o.y = f2bf(v[1]); o.z = f2bf(v[2]); o.w = f2bf(v[3]);
    ((ushort4*)out)[i] = o;
}

// ------------- leaky scan: bf16 in, bf16 out, fp32 state; 2 elems/thread -----
__global__ __launch_bounds__(256) void scan2_kernel(const u16* __restrict__ in,
                                                    u16* __restrict__ out,
                                                    const float* __restrict__ beta) {
    int i2   = blockIdx.x * 256 + threadIdx.x;   // 0 .. BHID/2-1
    int base = i2 * 2;
    int hh   = base & (HID - 1);
    float b0 = beta[hh], b1 = beta[hh + 1];
    float v0 = 0.f, v1 = 0.f;
    const u16* ip = in + base;
    u16*       op = out + base;
    for (int t = 0; t < T_STEPS; ++t) {
        ushort2 xv = *(const ushort2*)ip;
        v0 = b0 * v0 + bf2f(xv.x);
        v1 = b1 * v1 + bf2f(xv.y);
        ushort2 o; o.x = f2bf(v0); o.y = f2bf(v1);
        *(ushort2*)op = o;
        ip += BHID; op += BHID;
    }
}

// ---------------- 256x256 8-phase bf16 MFMA GEMM (dedup frag reads) ---------
// A: [M][K] bf16 row-major, B: [N][K] bf16 row-major. C row-major [M][N].
// 512 threads = 8 waves (2M x 4N). BK=64. LDS 128 KiB double-buffered.
// Per K-tile: P0 rd af0+bf0 -> Q(0,0); P1 rd af1 -> Q(1,0); P2 rd bf1 ->
// Q(0,1); P3 -> Q(1,1). 24 ds_read_b128/tile/wave (was 48).
// vmcnt discipline (FIFO accounting, per-wave count made workgroup-wide by
// placing the wait BEFORE the phase-final barrier):
//   prologue 10 loads, vmcnt(4)+bar; P0 end vmcnt(6) [retires A13(t)];
//   P3 end vmcnt(4) [retires A02(t+1)+B(t+1)].

#define GLDS16(g, l) __builtin_amdgcn_global_load_lds(                      \
        (const __attribute__((address_space(1))) void*)(g),                 \
        (__attribute__((address_space(3))) void*)(l), 16, 0, 0)

template <int RA, int RB, int QM, int QN, int VM, class S>
__device__ __forceinline__ void do_phase(const u16* lds, f32x4 (&acc)[8][4],
                                         s16x8 (&af)[2][4][2], s16x8 (&bf)[2][2][2],
                                         int ab, int bb, int sw0, int sw1,
                                         S&& stage) {
    if constexpr (RA >= 0) {
#pragma unroll
        for (int i = 0; i < 4; ++i) {
            const u16* p = lds + ab + (RA * 64 + i * 16) * 64;
            af[RA][i][0] = *(const s16x8*)(p + sw0);
            af[RA][i][1] = *(const s16x8*)(p + sw1);
        }
    }
    if constexpr (RB >= 0) {
#pragma unroll
        for (int j = 0; j < 2; ++j) {
            const u16* p = lds + bb + (RB * 32 + j * 16) * 64;
            bf[RB][j][0] = *(const s16x8*)(p + sw0);
            bf[RB][j][1] = *(const s16x8*)(p + sw1);
        }
    }
    stage();
    __builtin_amdgcn_s_barrier();
    __builtin_amdgcn_s_setprio(1);
#pragma unroll
    for (int i = 0; i < 4; ++i)
#pragma unroll
        for (int j = 0; j < 2; ++j) {
            acc[QM * 4 + i][QN * 2 + j] = __builtin_amdgcn_mfma_f32_16x16x32_bf16(
                af[QM][i][0], bf[QN][j][0], acc[QM * 4 + i][QN * 2 + j], 0, 0, 0);
            acc[QM * 4 + i][QN * 2 + j] = __builtin_amdgcn_mfma_f32_16x16x32_bf16(
                af[QM][i][1], bf[QN][j][1], acc[QM * 4 + i][QN * 2 + j], 0, 0, 0);
        }
    __builtin_amdgcn_s_setprio(0);
    if constexpr (VM == 6) asm volatile("s_waitcnt vmcnt(6)" ::: "memory");
    if constexpr (VM == 4) asm volatile("s_waitcnt vmcnt(4)" ::: "memory");
    __builtin_amdgcn_s_barrier();
}

template <bool RELU, typename OutT>
__global__ __launch_bounds__(512, 2) void gemm8(const u16* __restrict__ A,
                                                const u16* __restrict__ B,
                                                const float* __restrict__ bias,
                                                OutT* __restrict__ C,
                                                int N, int K) {
    __shared__ u16 lds[65536];   // [buf0: A 16K | B 16K][buf1: A 16K | B 16K]

    const int tid  = threadIdx.x;
    const int wv   = tid >> 6;
    const int lane = tid & 63;
    const int wr   = wv >> 2;     // 0..1 -> 128 rows
    const int wc   = wv & 3;      // 0..3 -> 64 cols
    const int lr   = lane & 15;

    // bijective XCD swizzle (m204) — grids 508/254 are not %8
    int nwg = gridDim.x, orig = blockIdx.x;
    int qq = nwg >> 3, rr = nwg & 7, xcd = orig & 7, lin = orig >> 3;
    int wg = (xcd < rr ? xcd * (qq + 1) : rr * (qq + 1) + (xcd - rr) * qq) + lin;

    const int NT = N >> 8;
    const int mt = wg / NT, nt = wg % NT;

    const u16* Ag = A + (size_t)mt * 256 * K;
    const u16* Bg = B + (size_t)nt * 256 * K;

    // staging geometry: one GLDS16 by 512 threads = 64 rows x 128 B
    const int grow  = tid >> 3;                       // row within 64-row load
    const int gcol  = 8 * ((tid & 7) ^ (grow & 7));   // swizzled elem col
    const int wbase = wv * 512;                       // wave's 8-row LDS block

#define STAGE_A(j, buf, kt) GLDS16(Ag + (size_t)((j) * 64 + grow) * K + (kt) + gcol, \
                                   lds + (buf) * 32768 + (j) * 4096 + wbase)
#define STAGE_B(j, buf, kt) GLDS16(Bg + (size_t)((j) * 64 + grow) * K + (kt) + gcol, \
                                   lds + (buf) * 32768 + 16384 + (j) * 4096 + wbase)

    // ds-read swizzle constants (row&7 == lane&7 for all fragment rows)
    const int sw0 = 8 * (((lane >> 4)) ^ (lane & 7));
    const int sw1 = 8 * ((4 | (lane >> 4)) ^ (lane & 7));
    const int arow = (wr * 128 + lr) * 64;
    const int brow = (wc * 64 + lr) * 64;

    f32x4 acc[8][4] = {};
    s16x8 af[2][4][2], bf[2][2][2];
    const int NKT = K >> 6;

    // prologue: tile0 (A02, B0-3, A13), tile1 A02  -> 10 loads in flight
    STAGE_A(0, 0, 0); STAGE_A(2, 0, 0);
    STAGE_B(0, 0, 0); STAGE_B(1, 0, 0); STAGE_B(2, 0, 0); STAGE_B(3, 0, 0);
    STAGE_A(1, 0, 0); STAGE_A(3, 0, 0);
    STAGE_A(0, 1, 64); STAGE_A(2, 1, 64);
    // retire tile0 A02+B for ALL waves before first read
    asm volatile("s_waitcnt vmcnt(4)" ::: "memory");
    __builtin_amdgcn_s_barrier();

    for (int t = 0; t < NKT; ++t) {
        const int buf = t & 1, nbuf = buf ^ 1;
        const int t1 = (t + 1 < NKT) ? t + 1 : NKT - 1;
        const int t2 = (t + 2 < NKT) ? t + 2 : NKT - 1;
        const int kt1 = t1 << 6, kt2 = t2 << 6;
        const int ab = buf * 32768 + arow;
        const int bb = buf * 32768 + 16384 + brow;

        // P0: rd af0+bf0 -> Q(0,0); stage B(t+1); vmcnt(6) retires A13(t)
        do_phase<0, 0, 0, 0, 6>(lds, acc, af, bf, ab, bb, sw0, sw1, [&] {
            STAGE_B(0, nbuf, kt1); STAGE_B(1, nbuf, kt1);
            STAGE_B(2, nbuf, kt1); STAGE_B(3, nbuf, kt1);
        });
        // P1: rd af1 -> Q(1,0); stage A13(t+1)
        do_phase<1, -1, 1, 0, -1>(lds, acc, af, bf, ab, bb, sw0, sw1, [&] {
            STAGE_A(1, nbuf, kt1); STAGE_A(3, nbuf, kt1);
        });
        // P2: rd bf1 -> Q(0,1); stage A02(t+2)
        do_phase<-1, 1, 0, 1, -1>(lds, acc, af, bf, ab, bb, sw0, sw1, [&] {
            STAGE_A(0, buf, kt2); STAGE_A(2, buf, kt2);
        });
        // P3: -> Q(1,1); vmcnt(4) retires A02(t+1)+B(t+1)
        do_phase<-1, -1, 1, 1, 4>(lds, acc, af, bf, ab, bb, sw0, sw1, [&] {});
    }

    // epilogue: C/D layout col = lane&15, row = (lane>>4)*4 + j.
    // n innermost so each row's 64-col span (1 full 128B line for bf16) is
    // written back-to-back -> L2 merges lines -> no write amplification.
    const int r0 = mt * 256 + wr * 128 + ((lane >> 4) << 2);
    const int c0 = nt * 256 + wc * 64 + lr;
    float bb4[4];
#pragma unroll
    for (int n = 0; n < 4; ++n) bb4[n] = bias[c0 + n * 16];
#pragma unroll
    for (int m = 0; m < 8; ++m)
#pragma unroll
        for (int j = 0; j < 4; ++j) {
            size_t rowoff = (size_t)(r0 + m * 16 + j) * N + c0;
#pragma unroll
            for (int n = 0; n < 4; ++n) {
                float v = acc[m][n][j] + bb4[n];
                if (RELU) v = v > 0.f ? v : 0.f;
                if constexpr (sizeof(OutT) == 2) C[rowoff + n * 16] = (OutT)f2bf(v);
                else                             C[rowoff + n * 16] = v;
            }
        }
#undef STAGE_A
#undef STAGE_B
}

// ---------------------------------------------------------------------------
extern "C" void kernel_launch(void* const* d_in, const int* in_sizes, int n_in,
                              void* d_out, int out_size, void* d_ws, size_t ws_size,
                              hipStream_t stream) {
    const float* x   = (const float*)d_in[0];
    const float* W1  = (const float*)d_in[1];
    const float* b1  = (const float*)d_in[2];
    const float* bt1 = (const float*)d_in[3];
    const float* W2  = (const float*)d_in[4];
    const float* b2  = (const float*)d_in[5];
    const float* bt2 = (const float*)d_in[6];
    const float* W3  = (const float*)d_in[7];
    const float* b3  = (const float*)d_in[8];
    const float* bt3 = (const float*)d_in[9];
    const float* W4  = (const float*)d_in[10];
    const float* b4  = (const float*)d_in[11];

    char* ws = (char*)d_ws;
    u16* h  = (u16*)ws;                                  // bf16 [M][H] GEMM out
    u16* hs = (u16*)(ws + (size_t)MROWS * HID * 2);      // bf16 [M][H] scan out
    u16* xb = hs;  // x_bf16 overlaps hs: consumed by GEMM1 before scan1 writes
    char* wp = ws + (size_t)MROWS * HID * 2 * 2;
    u16* W1b = (u16*)wp; wp += (size_t)HID * VOCAB * 2;
    u16* W2b = (u16*)wp; wp += (size_t)HID * HID * 2;
    u16* W3b = (u16*)wp; wp += (size_t)HID * HID * 2;
    u16* W4b = (u16*)wp;

    cvt_kernel<<<dim3((MROWS * VOCAB / 4 + 255) / 256), dim3(256), 0, stream>>>(
        x, xb, MROWS * VOCAB / 4);
    cvt_kernel<<<dim3(512),  dim3(256), 0, stream>>>(W1, W1b, HID * VOCAB / 4);
    cvt_kernel<<<dim3(1024), dim3(256), 0, stream>>>(W2, W2b, HID * HID / 4);
    cvt_kernel<<<dim3(1024), dim3(256), 0, stream>>>(W3, W3b, HID * HID / 4);
    cvt_kernel<<<dim3(512),  dim3(256), 0, stream>>>(W4, W4b, VOCAB * HID / 4);

    const int MT = MROWS / 256;  // 127

    // fc1 + scan1
    gemm8<false, u16><<<dim3(MT * (HID / 256)), dim3(512), 0, stream>>>(
        xb, W1b, b1, h, HID, VOCAB);
    scan2_kernel<<<dim3(BHID / 2 / 256), dim3(256), 0, stream>>>(h, hs, bt1);
    // fc2 (relu) + scan2
    gemm8<true, u16><<<dim3(MT * (HID / 256)), dim3(512), 0, stream>>>(
        hs, W2b, b2, h, HID, HID);
    scan2_kernel<<<dim3(BHID / 2 / 256), dim3(256), 0, stream>>>(h, hs, bt2);
    // fc3 (relu) + scan3
    gemm8<true, u16><<<dim3(MT * (HID / 256)), dim3(512), 0, stream>>>(
        hs, W3b, b3, h, HID, HID);
    scan2_kernel<<<dim3(BHID / 2 / 256), dim3(256), 0, stream>>>(h, hs, bt3);
    // fc4 -> d_out (fp32)
    gemm8<false, float><<<dim3(MT * (VOCAB / 256)), dim3(512), 0, stream>>>(
        hs, W4b, b4, (float*)d_out, VOCAB, HID);
}